// Round 7
// baseline (604.070 us; speedup 1.0000x reference)
//
#include <hip/hip_runtime.h>
#include <hip/hip_cooperative_groups.h>
namespace cg = cooperative_groups;

constexpr int NB    = 8;
constexpr int NN    = 256;
constexpr int F0    = 512;
constexpr int F1    = 256;
constexpr int F2    = 128;
constexpr int ROWS  = NB * NN;
constexpr int KMAX  = 30;
constexpr float INF = 1e30f;

// Skewed 256-float vector layout: chunk q (64 floats) at offset q*68 (bank-safe).
constexpr int VSTR = 272;
__device__ __forceinline__ int cmap(int j) { return (j >> 6) * 68 + (j & 63); }

struct __align__(16) SmemT {
  union {
    struct { float As[16][64]; float Bs[16][64]; } mm;   // 8 KB
    struct { float As[16][64]; float Bs[16][32]; } ge;   // 6 KB
    double Pw[1024];                                     // 8 KB
    double diag[NN];                                     // 2 KB
    float  cs[4 * VSTR];                                 // 4.3 KB
    struct { float cprev[VSTR]; float mrow[NN]; float ivh[NN]; } sm;  // 3.1 KB
  } u;
};

// upper-triangular 4x4 tile list (10 tiles)
__device__ __constant__ int TRt[10] = {0,0,0,0,1,1,1,2,2,3};
__device__ __constant__ int TCt[10] = {0,1,2,3,1,2,3,2,3,3};

// ---------------- 64x32 GEMM tile: C = act(A@B + bias) -------------------------
__device__ __forceinline__ void gemm_tile(
    const float* __restrict__ A, const float* __restrict__ B,
    const float* __restrict__ bias, float* __restrict__ C,
    int Ncols, int K, int relu, int rowBase, int colBase, SmemT& s)
{
  const int tid = threadIdx.x;
  const int tx = tid & 15, ty = tid >> 4;
  float acc[4][2] = {};
  for (int k0 = 0; k0 < K; k0 += 16) {
    {
      const int r  = tid >> 2;
      const int kq = (tid & 3) << 2;
      const float4 av = *(const float4*)(A + (size_t)(rowBase + r) * K + k0 + kq);
      s.u.ge.As[kq+0][r] = av.x; s.u.ge.As[kq+1][r] = av.y;
      s.u.ge.As[kq+2][r] = av.z; s.u.ge.As[kq+3][r] = av.w;
      const int kr = tid >> 4;
      const int c2 = (tid & 15) << 1;
      const float2 bv = *(const float2*)(B + (size_t)(k0 + kr) * Ncols + colBase + c2);
      s.u.ge.Bs[kr][c2+0] = bv.x; s.u.ge.Bs[kr][c2+1] = bv.y;
    }
    __syncthreads();
    #pragma unroll
    for (int kk = 0; kk < 16; kk++) {
      const float4 a = *(const float4*)&s.u.ge.As[kk][ty*4];
      const float b0v = s.u.ge.Bs[kk][tx*2+0];
      const float b1v = s.u.ge.Bs[kk][tx*2+1];
      acc[0][0] += a.x*b0v; acc[0][1] += a.x*b1v;
      acc[1][0] += a.y*b0v; acc[1][1] += a.y*b1v;
      acc[2][0] += a.z*b0v; acc[2][1] += a.z*b1v;
      acc[3][0] += a.w*b0v; acc[3][1] += a.w*b1v;
    }
    __syncthreads();
  }
  #pragma unroll
  for (int i = 0; i < 4; i++) {
    const int rr = rowBase + ty*4 + i;
    #pragma unroll
    for (int j = 0; j < 2; j++) {
      const int cc = colBase + tx*2 + j;
      float v = acc[i][j] + bias[cc];
      if (relu) v = fmaxf(v, 0.0f);
      C[(size_t)rr * Ncols + cc] = v;
    }
  }
}

// ---------------- corr tile: D = 0.5*(1 - cos-sim), norms inline ---------------
__device__ __forceinline__ void corr_tile(
    const float* __restrict__ z, float* __restrict__ D,
    int b, int rg, int cg, SmemT& s)
{
  const float* zb = z + (size_t)b * NN * F2;
  const int tid = threadIdx.x;
  const int tx = tid & 15, ty = tid >> 4;
  const int rowBase = rg * 64, colBase = cg * 64;
  float acc[4][4] = {};
  float rn[4] = {}, cn[4] = {};
  for (int k0 = 0; k0 < F2; k0 += 16) {
    {
      const int r  = tid >> 2;
      const int kq = (tid & 3) << 2;
      const float4 av = *(const float4*)(zb + (size_t)(rowBase + r) * F2 + k0 + kq);
      s.u.mm.As[kq+0][r] = av.x; s.u.mm.As[kq+1][r] = av.y;
      s.u.mm.As[kq+2][r] = av.z; s.u.mm.As[kq+3][r] = av.w;
      const float4 bv = *(const float4*)(zb + (size_t)(colBase + r) * F2 + k0 + kq);
      s.u.mm.Bs[kq+0][r] = bv.x; s.u.mm.Bs[kq+1][r] = bv.y;
      s.u.mm.Bs[kq+2][r] = bv.z; s.u.mm.Bs[kq+3][r] = bv.w;
    }
    __syncthreads();
    #pragma unroll
    for (int kk = 0; kk < 16; kk++) {
      const float4 a  = *(const float4*)&s.u.mm.As[kk][ty*4];
      const float4 bq = *(const float4*)&s.u.mm.Bs[kk][tx*4];
      const float ar[4] = {a.x, a.y, a.z, a.w};
      const float br[4] = {bq.x, bq.y, bq.z, bq.w};
      #pragma unroll
      for (int i = 0; i < 4; i++) {
        rn[i] += ar[i] * ar[i];
        cn[i] += br[i] * br[i];
        #pragma unroll
        for (int j = 0; j < 4; j++)
          acc[i][j] += ar[i] * br[j];
      }
    }
    __syncthreads();
  }
  float* Db = D + (size_t)b * NN * NN;
  #pragma unroll
  for (int i = 0; i < 4; i++) {
    const int rr = rowBase + ty*4 + i;
    #pragma unroll
    for (int j = 0; j < 4; j++) {
      const int cc = colBase + tx*4 + j;
      const float denom = sqrtf(fmaxf(rn[i] * cn[j], 1e-8f));
      Db[(size_t)rr * NN + cc] = 0.5f * (1.0f - acc[i][j] / denom);
    }
  }
}

// ---------------- row scan (fp64) over 64 rows of group (b,g) ------------------
__device__ __forceinline__ void rowscan_blk(
    const float* __restrict__ D, double* __restrict__ R, double* __restrict__ Pg,
    int b, int g, SmemT& s)
{
  const int tid = threadIdx.x, w = tid >> 6, lane = tid & 63;
  double pr0 = 0, pr1 = 0, pr2 = 0, pr3 = 0;
  for (int t = 0; t < 16; t++) {
    const int n = g*64 + w*16 + t;
    const float4 dv = *(const float4*)(D + ((size_t)b*NN + n)*NN + lane*4);
    double p0 = dv.x, p1 = p0 + dv.y, p2 = p1 + dv.z, p3 = p2 + dv.w;
    double tt = p3;
    #pragma unroll
    for (int d = 1; d < 64; d <<= 1) {
      double uu = __shfl_up(tt, d);
      if (lane >= d) tt += uu;
    }
    const double off = tt - p3;
    const double v0 = off+p0, v1 = off+p1, v2 = off+p2, v3 = off+p3;
    double* rr = R + ((size_t)b*NN + n)*NN + lane*4;
    rr[0]=v0; rr[1]=v1; rr[2]=v2; rr[3]=v3;
    pr0 += v0; pr1 += v1; pr2 += v2; pr3 += v3;
  }
  s.u.Pw[w*256 + lane*4 + 0] = pr0;
  s.u.Pw[w*256 + lane*4 + 1] = pr1;
  s.u.Pw[w*256 + lane*4 + 2] = pr2;
  s.u.Pw[w*256 + lane*4 + 3] = pr3;
  __syncthreads();
  Pg[((size_t)b*4 + g)*NN + tid] =
      s.u.Pw[tid] + s.u.Pw[256+tid] + s.u.Pw[512+tid] + s.u.Pw[768+tid];
}

// ---------------- column scan (64-deep) + diag extraction ----------------------
__device__ __forceinline__ void colscan_blk(
    const double* __restrict__ R, const double* __restrict__ Pg,
    double* __restrict__ S, double* __restrict__ dg, int b, int g)
{
  const int j = threadIdx.x;
  double ofs = 0.0;
  for (int gp = 0; gp < g; gp++) ofs += Pg[((size_t)b*4 + gp)*NN + j];
  const double* Rb = R + ((size_t)b*NN + g*64)*NN;
  double*       Sb = S + ((size_t)b*NN + g*64)*NN;
  double cum = ofs;
  for (int r = 0; r < 64; r += 4) {
    const double d0 = Rb[(size_t)(r+0)*NN + j];
    const double d1 = Rb[(size_t)(r+1)*NN + j];
    const double d2 = Rb[(size_t)(r+2)*NN + j];
    const double d3 = Rb[(size_t)(r+3)*NN + j];
    cum += d0; Sb[(size_t)(r+0)*NN + j] = cum; if (g*64+r+0 == j) dg[b*NN + j] = cum;
    cum += d1; Sb[(size_t)(r+1)*NN + j] = cum; if (g*64+r+1 == j) dg[b*NN + j] = cum;
    cum += d2; Sb[(size_t)(r+2)*NN + j] = cum; if (g*64+r+2 == j) dg[b*NN + j] = cum;
    cum += d3; Sb[(size_t)(r+3)*NN + j] = cum; if (g*64+r+3 == j) dg[b*NN + j] = cum;
  }
}

// ---------------- Ds -> A (shifted), C0 -> Cstk[0], out init -------------------
__device__ __forceinline__ void dsmat_blk(
    const double* __restrict__ S, const double* __restrict__ dg,
    float* __restrict__ A, float* __restrict__ Cstk, float* __restrict__ out,
    int b, int rg, SmemT& s)
{
  const int j = threadIdx.x;
  s.u.diag[j] = dg[(size_t)b*NN + j];
  __syncthreads();
  const double* Sb = S + (size_t)b*NN*NN;
  float* Ab = A + (size_t)b*NN*NN;
  const double dj = s.u.diag[j];
  for (int t = 0; t < 64; t++) {
    const int n = rg*64 + t;
    double snn = 0.0, sv = 0.0;
    if (n > 0) { snn = s.u.diag[n-1]; sv = Sb[(size_t)(n-1)*NN + j]; }
    const float ds = (j >= n) ? (float)(dj - 2.0*sv + snn) : INF;
    if (j < NN-1) Ab[(size_t)n*NN + j + 1] = ds;
    else          Cstk[(size_t)b*32*NN + n] = ds;   // C0[n] = Ds[n][N-1]
    if (j == 0)   Ab[(size_t)n*NN] = INF;
  }
  if (rg == 0) out[b*NN + j] = (j == NN-1) ? 1.0f : 0.0f;
}

// ---------------- min-plus MM tile (upper tiles only) --------------------------
__device__ __forceinline__ void mm_tile(
    const float* __restrict__ P, const float* __restrict__ Q, float* __restrict__ O,
    int b, int rowBase, int colBase, SmemT& s)
{
  const int tid = threadIdx.x;
  const int tx = tid & 15, ty = tid >> 4;
  const float* Pb = P + (size_t)b*NN*NN;
  const float* Qb = Q + (size_t)b*NN*NN;
  float acc[4][4];
  #pragma unroll
  for (int i = 0; i < 4; i++)
    #pragma unroll
    for (int j = 0; j < 4; j++) acc[i][j] = INF;
  const int kHi = (colBase + 64 < NN) ? colBase + 64 : NN;
  for (int k0 = rowBase; k0 < kHi; k0 += 16) {
    {
      const int r  = tid >> 2;
      const int kq = (tid & 3) << 2;
      const float4 av = *(const float4*)(Pb + (size_t)(rowBase + r)*NN + k0 + kq);
      s.u.mm.As[kq+0][r] = av.x; s.u.mm.As[kq+1][r] = av.y;
      s.u.mm.As[kq+2][r] = av.z; s.u.mm.As[kq+3][r] = av.w;
      const int kr = tid >> 4;
      const int c4 = (tid & 15) << 2;
      *(float4*)&s.u.mm.Bs[kr][c4] =
          *(const float4*)(Qb + (size_t)(k0 + kr)*NN + colBase + c4);
    }
    __syncthreads();
    #pragma unroll
    for (int kk = 0; kk < 16; kk++) {
      const float4 a  = *(const float4*)&s.u.mm.As[kk][ty*4];
      const float4 bq = *(const float4*)&s.u.mm.Bs[kk][tx*4];
      const float ar[4] = {a.x, a.y, a.z, a.w};
      const float br[4] = {bq.x, bq.y, bq.z, bq.w};
      #pragma unroll
      for (int i = 0; i < 4; i++)
        #pragma unroll
        for (int j = 0; j < 4; j++)
          acc[i][j] = fminf(acc[i][j], ar[i] + br[j]);
    }
    __syncthreads();
  }
  float* Ob = O + (size_t)b*NN*NN;
  #pragma unroll
  for (int i = 0; i < 4; i++)
    #pragma unroll
    for (int j = 0; j < 4; j++)
      Ob[(size_t)(rowBase + ty*4 + i)*NN + colBase + tx*4 + j] =
          fminf(acc[i][j], INF);
}

// ---------------- chain stage: C_{kout+v0+v} = P (x) C_{kin+v0+v} --------------
__device__ __forceinline__ void stage_blk(
    const float* __restrict__ P, float* __restrict__ Cstk,
    int b, int rg, int vc, int kin, int kout, int nvTot, float* cs)
{
  const int v0 = vc * 4;
  const int nvb = min(4, nvTot - v0);
  const int tid = threadIdx.x;
  float* Ck = Cstk + (size_t)b*32*NN;
  for (int v = 0; v < nvb; v++)
    cs[v*VSTR + cmap(tid)] = Ck[(size_t)(kin + v0 + v)*NN + tid];
  __syncthreads();
  const int n = rg*64 + (tid >> 2);
  const int q = tid & 3;
  const float* Pr = P + (size_t)b*NN*NN + (size_t)n*NN + q*64;
  float m[4] = {INF, INF, INF, INF};
  if (q*64 + 63 > n) {
    #pragma unroll 4
    for (int i = 0; i < 16; i++) {
      const float4 a = *(const float4*)(Pr + i*4);
      #pragma unroll
      for (int v = 0; v < 4; v++) {
        if (v < nvb) {
          const float4 c = *(const float4*)&cs[v*VSTR + q*68 + i*4];
          m[v] = fminf(m[v], fminf(fminf(a.x + c.x, a.y + c.y),
                                   fminf(a.z + c.z, a.w + c.w)));
        }
      }
    }
  }
  #pragma unroll
  for (int v = 0; v < 4; v++) {
    m[v] = fminf(m[v], __shfl_xor(m[v], 1));
    m[v] = fminf(m[v], __shfl_xor(m[v], 2));
  }
  if (q == 0) {
    for (int v = 0; v < nvb; v++)
      Ck[(size_t)(kout + v0 + v)*NN + n] = fminf(m[v], INF);
  }
}

// ---------------- fused softmax for one (k,b): rows then cols ------------------
__device__ __forceinline__ void sm_blk(
    const float* __restrict__ A, const float* __restrict__ Cstk,
    float* __restrict__ out, int b, int k, SmemT& s)
{
  const int limit = NN - k;
  const int tid = threadIdx.x;
  const float* Ckb = Cstk + (size_t)b*32*NN;
  s.u.sm.cprev[cmap(tid)] = Ckb[(size_t)(k-1)*NN + tid];
  s.u.sm.mrow[tid]        = Ckb[(size_t)k*NN + tid];
  __syncthreads();
  const float* Ab = A + (size_t)b*NN*NN;
  const int r = tid >> 2, q = tid & 3;
  for (int rr2 = 0; rr2 < 4; rr2++) {
    const int n = rr2*64 + r;
    const float m = s.u.sm.mrow[n];
    float sum = 0.f;
    if (q*64 + 63 > n) {
      const float* Ar = Ab + (size_t)n*NN + q*64;
      #pragma unroll 4
      for (int i = 0; i < 16; i++) {
        const float4 a = *(const float4*)(Ar + i*4);
        const int jj = q*64 + i*4;
        const float4 c = *(const float4*)&s.u.sm.cprev[q*68 + i*4];
        sum += (jj + 0 <= limit) ? __expf(m - a.x - c.x) : 0.f;
        sum += (jj + 1 <= limit) ? __expf(m - a.y - c.y) : 0.f;
        sum += (jj + 2 <= limit) ? __expf(m - a.z - c.z) : 0.f;
        sum += (jj + 3 <= limit) ? __expf(m - a.w - c.w) : 0.f;
      }
    }
    sum += __shfl_xor(sum, 1);
    sum += __shfl_xor(sum, 2);
    if (q == 0) s.u.sm.ivh[n] = 1.0f / sum;
  }
  __syncthreads();
  const int j = tid;
  if (j < limit) {
    const float cj = s.u.sm.cprev[cmap(j + 1)];
    const int nmax = (j < limit - 1) ? j : limit - 1;
    float a = 0.0f;
    for (int nr = 0; nr <= nmax; nr++)
      a += __expf(s.u.sm.mrow[nr] - Ab[(size_t)nr*NN + j + 1] - cj) * s.u.sm.ivh[nr];
    int kmaxj = NN - 1 - j; if (kmaxj > KMAX - 1) kmaxj = KMAX - 1;
    atomicAdd(&out[b*NN + j], a / (float)((j + 1) * kmaxj));
  }
}

// ---------------- the single cooperative mega-kernel ---------------------------
__global__ __launch_bounds__(256) void mega(
    const float* __restrict__ x,  const float* __restrict__ W0,
    const float* __restrict__ b0, const float* __restrict__ W1,
    const float* __restrict__ b1,
    float* h, float* z, float* D, double* R, double* Pg, double* dg, double* S,
    float* A, float* A2, float* A4, float* A8, float* A16,
    float* Cstk, float* out)
{
  cg::grid_group grid = cg::this_grid();
  __shared__ SmemT s;
  const int u = blockIdx.x;

  // P0: h = relu(x@W0+b0) — 256 tiles (32 row x 8 col of 64x32)
  gemm_tile(x, W0, b0, h, F1, F0, 1, (u >> 3) * 64, (u & 7) * 32, s);
  grid.sync();
  // P1: z = h@W1+b1 — 128 tiles
  if (u < 128) gemm_tile(h, W1, b1, z, F2, F1, 0, (u >> 2) * 64, (u & 3) * 32, s);
  grid.sync();
  // P2: D — 128 tiles (b, rg, cg)
  if (u < 128) corr_tile(z, D, u >> 4, (u >> 2) & 3, u & 3, s);
  grid.sync();
  // P3: row scans + group partials — 32 units (b, g)
  if (u < 32) rowscan_blk(D, R, Pg, u >> 2, u & 3, s);
  grid.sync();
  // P4: column scans — 32 units
  if (u < 32) colscan_blk(R, Pg, S, dg, u >> 2, u & 3);
  grid.sync();
  // P5: A, C0, out init — 32 units
  if (u < 32) dsmat_blk(S, dg, A, Cstk, out, u >> 2, u & 3, s);
  grid.sync();
  // P6: A2 = A(x)A — 80 upper tiles
  if (u < 128 && (u & 15) < 10)
    mm_tile(A, A, A2, u >> 4, TRt[u & 15] * 64, TCt[u & 15] * 64, s);
  grid.sync();
  // P7: A4 = A2(x)A2  +  C1 = A(x)C0
  if (u < 128) { if ((u & 15) < 10)
    mm_tile(A2, A2, A4, u >> 4, TRt[u & 15] * 64, TCt[u & 15] * 64, s); }
  else if (u < 160) { const int xx = u - 128;
    stage_blk(A, Cstk, xx >> 2, xx & 3, 0, 0, 1, 1, s.u.cs); }
  grid.sync();
  // P8: A8 = A4(x)A4  +  C2-3 = A2(x)C0-1
  if (u < 128) { if ((u & 15) < 10)
    mm_tile(A4, A4, A8, u >> 4, TRt[u & 15] * 64, TCt[u & 15] * 64, s); }
  else if (u < 160) { const int xx = u - 128;
    stage_blk(A2, Cstk, xx >> 2, xx & 3, 0, 0, 2, 2, s.u.cs); }
  grid.sync();
  // P9: A16 = A8(x)A8  +  C4-7 = A4(x)C0-3
  if (u < 128) { if ((u & 15) < 10)
    mm_tile(A8, A8, A16, u >> 4, TRt[u & 15] * 64, TCt[u & 15] * 64, s); }
  else if (u < 160) { const int xx = u - 128;
    stage_blk(A4, Cstk, xx >> 2, xx & 3, 0, 0, 4, 4, s.u.cs); }
  grid.sync();
  // P10: C8-15 = A8(x)C0-7 — 64 units (b, rg, vc<2)
  if (u < 64) stage_blk(A8, Cstk, u >> 3, u & 3, (u & 7) >> 2, 0, 8, 8, s.u.cs);
  grid.sync();
  // P11: C16-29 = A16(x)C0-13 — 128 units (b, rg, vc<4)
  if (u < 128) stage_blk(A16, Cstk, u >> 4, u & 3, (u & 15) >> 2, 0, 16, 14, s.u.cs);
  grid.sync();
  // P12: softmax accumulate — 232 units (k, b)
  if (u < 232) sm_blk(A, Cstk, out, u & 7, (u >> 3) + 1, s);
}

extern "C" void kernel_launch(void* const* d_in, const int* in_sizes, int n_in,
                              void* d_out, int out_size, void* d_ws, size_t ws_size,
                              hipStream_t stream) {
  const float* x  = (const float*)d_in[0];
  const float* W0 = (const float*)d_in[1];
  const float* b0 = (const float*)d_in[2];
  const float* W1 = (const float*)d_in[3];
  const float* b1 = (const float*)d_in[4];
  float* out = (float*)d_out;

  // ws layout — non-overlapping, ~26 MB of the 256 MiB workspace
  char* base = (char*)d_ws;
  float*  h    = (float*)(base);                          // 2 MB
  float*  z    = (float*)(base + (2u  << 20));            // 1 MB
  float*  D    = (float*)(base + (3u  << 20));            // 2 MB
  double* R    = (double*)(base + (5u  << 20));           // 4 MB
  double* S    = (double*)(base + (9u  << 20));           // 4 MB
  double* Pg   = (double*)(base + (13u << 20));           // 64 KB
  double* dg   = (double*)(base + (13u << 20) + (128u << 10));  // 16 KB
  float*  A    = (float*)(base + (14u << 20));            // 2 MB
  float*  A2   = (float*)(base + (16u << 20));
  float*  A4   = (float*)(base + (18u << 20));
  float*  A8   = (float*)(base + (20u << 20));
  float*  A16  = (float*)(base + (22u << 20));
  float*  Cstk = (float*)(base + (24u << 20));            // 256 KB

  void* args[] = { &x, &W0, &b0, &W1, &b1, &h, &z, &D, &R, &Pg, &dg, &S,
                   &A, &A2, &A4, &A8, &A16, &Cstk, &out };
  hipLaunchCooperativeKernel(reinterpret_cast<void*>(mega),
                             dim3(256), dim3(256), args, 0, stream);
}

// Round 8
// 319.802 us; speedup vs baseline: 1.8889x; 1.8889x over previous
//
#include <hip/hip_runtime.h>

constexpr int NB    = 8;
constexpr int NN    = 256;
constexpr int F0    = 512;
constexpr int F1    = 256;
constexpr int F2    = 128;
constexpr int ROWS  = NB * NN;
constexpr int KMAX  = 30;
constexpr float INF = 1e30f;

// Skewed 256-float vector layout: chunk q (64 floats) at offset q*68 (bank-safe).
constexpr int VSTR = 272;
__device__ __forceinline__ int cmap(int j) { return (j >> 6) * 68 + (j & 63); }

// ---------------- fp32 GEMM: C = act(A @ B + bias), 64x64 tile, BK=16 ----------
__global__ __launch_bounds__(256) void gemm64(
    const float* __restrict__ A, const float* __restrict__ B,
    const float* __restrict__ bias, float* __restrict__ C,
    int M, int Ncols, int K, int relu)
{
  __shared__ float As[16][64];
  __shared__ float Bs[16][64];
  const int tid = threadIdx.x;
  const int tx = tid & 15;
  const int ty = tid >> 4;
  const int rowBase = blockIdx.y * 64;
  const int colBase = blockIdx.x * 64;
  float acc[4][4] = {};
  for (int k0 = 0; k0 < K; k0 += 16) {
    {
      const int r  = tid >> 2;
      const int kq = (tid & 3) << 2;
      const float4 av = *(const float4*)(A + (size_t)(rowBase + r) * K + (k0 + kq));
      As[kq+0][r] = av.x; As[kq+1][r] = av.y; As[kq+2][r] = av.z; As[kq+3][r] = av.w;
      const int kr = tid >> 4;
      const int c4 = (tid & 15) << 2;
      *(float4*)&Bs[kr][c4] = *(const float4*)(B + (size_t)(k0 + kr) * Ncols + (colBase + c4));
    }
    __syncthreads();
    #pragma unroll
    for (int kk = 0; kk < 16; kk++) {
      const float4 a = *(const float4*)&As[kk][ty*4];
      const float4 b4 = *(const float4*)&Bs[kk][tx*4];
      const float ar[4] = {a.x, a.y, a.z, a.w};
      const float br[4] = {b4.x, b4.y, b4.z, b4.w};
      #pragma unroll
      for (int i = 0; i < 4; i++)
        #pragma unroll
        for (int j = 0; j < 4; j++)
          acc[i][j] += ar[i] * br[j];
    }
    __syncthreads();
  }
  #pragma unroll
  for (int i = 0; i < 4; i++) {
    const int rr = rowBase + ty*4 + i;
    float4 v;
    float* vp = &v.x;
    #pragma unroll
    for (int j = 0; j < 4; j++) {
      float t = acc[i][j] + bias[colBase + tx*4 + j];
      vp[j] = relu ? fmaxf(t, 0.0f) : t;
    }
    *(float4*)(C + (size_t)rr * Ncols + colBase + tx*4) = v;
  }
}

// ---------------- D[b,n,m] = 0.5*(1 - cos-sim), norms inline -------------------
__global__ __launch_bounds__(256) void corr_dist(
    const float* __restrict__ z, float* __restrict__ D)
{
  const int b = blockIdx.z;
  const float* zb = z + (size_t)b * NN * F2;
  __shared__ float As[16][64];
  __shared__ float Bs[16][64];
  const int tid = threadIdx.x;
  const int tx = tid & 15;
  const int ty = tid >> 4;
  const int rowBase = blockIdx.y * 64;
  const int colBase = blockIdx.x * 64;
  float acc[4][4] = {};
  float rn[4] = {}, cn[4] = {};
  for (int k0 = 0; k0 < F2; k0 += 16) {
    {
      const int r  = tid >> 2;
      const int kq = (tid & 3) << 2;
      const float4 av = *(const float4*)(zb + (size_t)(rowBase + r) * F2 + (k0 + kq));
      As[kq+0][r] = av.x; As[kq+1][r] = av.y; As[kq+2][r] = av.z; As[kq+3][r] = av.w;
      const float4 bv = *(const float4*)(zb + (size_t)(colBase + r) * F2 + (k0 + kq));
      Bs[kq+0][r] = bv.x; Bs[kq+1][r] = bv.y; Bs[kq+2][r] = bv.z; Bs[kq+3][r] = bv.w;
    }
    __syncthreads();
    #pragma unroll
    for (int kk = 0; kk < 16; kk++) {
      const float4 a = *(const float4*)&As[kk][ty*4];
      const float4 bq = *(const float4*)&Bs[kk][tx*4];
      const float ar[4] = {a.x, a.y, a.z, a.w};
      const float br[4] = {bq.x, bq.y, bq.z, bq.w};
      #pragma unroll
      for (int i = 0; i < 4; i++) {
        rn[i] += ar[i] * ar[i];
        cn[i] += br[i] * br[i];
        #pragma unroll
        for (int j = 0; j < 4; j++)
          acc[i][j] += ar[i] * br[j];
      }
    }
    __syncthreads();
  }
  float* Db = D + (size_t)b * NN * NN;
  #pragma unroll
  for (int i = 0; i < 4; i++) {
    const int rr = rowBase + ty*4 + i;
    #pragma unroll
    for (int j = 0; j < 4; j++) {
      const int cc = colBase + tx*4 + j;
      const float denom = sqrtf(fmaxf(rn[i] * cn[j], 1e-8f));
      Db[(size_t)rr * NN + cc] = 0.5f * (1.0f - acc[i][j] / denom);
    }
  }
}

// ---------------- row scans (fp64) + group column partials: block (b,g) --------
__global__ __launch_bounds__(256) void rowscan_pg(
    const float* __restrict__ D, double* __restrict__ R, double* __restrict__ Pg)
{
  const int g = blockIdx.x & 3, b = blockIdx.x >> 2;
  __shared__ double Pw[1024];
  const int tid = threadIdx.x, w = tid >> 6, lane = tid & 63;
  double pr0 = 0, pr1 = 0, pr2 = 0, pr3 = 0;
  for (int t = 0; t < 16; t++) {
    const int n = g*64 + w*16 + t;
    const float4 dv = *(const float4*)(D + ((size_t)b*NN + n)*NN + lane*4);
    double p0 = dv.x, p1 = p0 + dv.y, p2 = p1 + dv.z, p3 = p2 + dv.w;
    double tt = p3;
    #pragma unroll
    for (int d = 1; d < 64; d <<= 1) {
      double uu = __shfl_up(tt, d);
      if (lane >= d) tt += uu;
    }
    const double off = tt - p3;
    const double v0 = off+p0, v1 = off+p1, v2 = off+p2, v3 = off+p3;
    double* rr = R + ((size_t)b*NN + n)*NN + lane*4;
    rr[0]=v0; rr[1]=v1; rr[2]=v2; rr[3]=v3;
    pr0 += v0; pr1 += v1; pr2 += v2; pr3 += v3;
  }
  Pw[w*256 + lane*4 + 0] = pr0;
  Pw[w*256 + lane*4 + 1] = pr1;
  Pw[w*256 + lane*4 + 2] = pr2;
  Pw[w*256 + lane*4 + 3] = pr3;
  __syncthreads();
  Pg[((size_t)b*4 + g)*NN + tid] =
      Pw[tid] + Pw[256+tid] + Pw[512+tid] + Pw[768+tid];
}

// ---------------- column scan (64-deep) + diag extraction: block (rg, b) -------
__global__ __launch_bounds__(256) void colscan2(
    const double* __restrict__ R, const double* __restrict__ Pg,
    double* __restrict__ S, double* __restrict__ dg)
{
  const int rg = blockIdx.x, b = blockIdx.y, j = threadIdx.x;
  double ofs = 0.0;
  for (int g = 0; g < rg; g++) ofs += Pg[((size_t)b * 4 + g) * NN + j];
  const double* Rb = R + ((size_t)(b * NN + rg * 64)) * NN;
  double*       Sb = S + ((size_t)(b * NN + rg * 64)) * NN;
  double cum = ofs;
  for (int r = 0; r < 64; r += 4) {
    const double d0 = Rb[(size_t)(r+0)*NN + j];
    const double d1 = Rb[(size_t)(r+1)*NN + j];
    const double d2 = Rb[(size_t)(r+2)*NN + j];
    const double d3 = Rb[(size_t)(r+3)*NN + j];
    cum += d0; Sb[(size_t)(r+0)*NN + j] = cum; if (rg*64 + r + 0 == j) dg[b*NN + j] = cum;
    cum += d1; Sb[(size_t)(r+1)*NN + j] = cum; if (rg*64 + r + 1 == j) dg[b*NN + j] = cum;
    cum += d2; Sb[(size_t)(r+2)*NN + j] = cum; if (rg*64 + r + 2 == j) dg[b*NN + j] = cum;
    cum += d3; Sb[(size_t)(r+3)*NN + j] = cum; if (rg*64 + r + 3 == j) dg[b*NN + j] = cum;
  }
}

// ---------------- Ds -> A (shifted), C0 -> Cstk[0], out init: block (rg, b) ----
__global__ __launch_bounds__(256) void dsmat(
    const double* __restrict__ S, const double* __restrict__ dg,
    float* __restrict__ A, float* __restrict__ Cstk, float* __restrict__ out)
{
  const int rg = blockIdx.x, b = blockIdx.y, j = threadIdx.x;
  __shared__ double diag[NN];
  diag[j] = dg[(size_t)b * NN + j];
  __syncthreads();
  const double* Sb = S + (size_t)b * NN * NN;
  float* Ab = A + (size_t)b * NN * NN;
  const double dj = diag[j];
  for (int t = 0; t < 64; t++) {
    const int n = rg * 64 + t;
    double snn = 0.0, sv = 0.0;
    if (n > 0) { snn = diag[n-1]; sv = Sb[(size_t)(n-1)*NN + j]; }
    const float ds = (j >= n) ? (float)(dj - 2.0 * sv + snn) : INF;
    if (j < NN - 1) Ab[(size_t)n * NN + j + 1] = ds;
    else            Cstk[(size_t)b * 32 * NN + n] = ds;    // C0[n] = Ds[n][N-1]
    if (j == 0)     Ab[(size_t)n * NN] = INF;
  }
  if (rg == 0) out[b * NN + j] = (j == NN - 1) ? 1.0f : 0.0f;
}

// ---------------- unified tail: min-plus MM tiles + chain stages ---------------
__device__ __forceinline__ void mm_tile(
    const float* __restrict__ P, const float* __restrict__ Q, float* __restrict__ O,
    int b, int x, float (*As)[64], float (*Bs)[64])
{
  const int tid = threadIdx.x;
  const int tx = tid & 15;
  const int ty = tid >> 4;
  const int rowBase = (x >> 2) * 64;
  const int colBase = (x & 3) * 64;
  float* Ob = O + (size_t)b * NN * NN;
  if (colBase < rowBase) {
    #pragma unroll
    for (int i = 0; i < 4; i++)
      #pragma unroll
      for (int j = 0; j < 4; j++)
        Ob[(size_t)(rowBase + ty*4 + i) * NN + (colBase + tx*4 + j)] = INF;
    return;
  }
  const float* Pb = P + (size_t)b * NN * NN;
  const float* Qb = Q + (size_t)b * NN * NN;
  float acc[4][4];
  #pragma unroll
  for (int i = 0; i < 4; i++)
    #pragma unroll
    for (int j = 0; j < 4; j++) acc[i][j] = INF;
  const int kHi = (colBase + 64 < NN) ? colBase + 64 : NN;
  for (int k0 = rowBase; k0 < kHi; k0 += 16) {
    {
      const int r  = tid >> 2;
      const int kq = (tid & 3) << 2;
      const float4 av = *(const float4*)(Pb + (size_t)(rowBase + r) * NN + (k0 + kq));
      As[kq+0][r] = av.x; As[kq+1][r] = av.y; As[kq+2][r] = av.z; As[kq+3][r] = av.w;
      const int kr = tid >> 4;
      const int c4 = (tid & 15) << 2;
      *(float4*)&Bs[kr][c4] = *(const float4*)(Qb + (size_t)(k0 + kr) * NN + (colBase + c4));
    }
    __syncthreads();
    #pragma unroll
    for (int kk = 0; kk < 16; kk++) {
      const float4 a = *(const float4*)&As[kk][ty*4];
      const float4 bq = *(const float4*)&Bs[kk][tx*4];
      const float ar[4] = {a.x, a.y, a.z, a.w};
      const float br[4] = {bq.x, bq.y, bq.z, bq.w};
      #pragma unroll
      for (int i = 0; i < 4; i++)
        #pragma unroll
        for (int j = 0; j < 4; j++)
          acc[i][j] = fminf(acc[i][j], ar[i] + br[j]);
    }
    __syncthreads();
  }
  #pragma unroll
  for (int i = 0; i < 4; i++)
    #pragma unroll
    for (int j = 0; j < 4; j++)
      Ob[(size_t)(rowBase + ty*4 + i) * NN + (colBase + tx*4 + j)] =
          fminf(acc[i][j], INF);
}

__device__ __forceinline__ void stage_blk(
    const float* __restrict__ P, float* __restrict__ Cstk,
    int b, int x, int kin, int kout, int nv, float* cs)
{
  const int vc = x >> 2, rg = x & 3;
  const int v0 = vc * 4;
  if (v0 >= nv) return;
  const int nvb = min(4, nv - v0);
  const int tid = threadIdx.x;
  float* Ck = Cstk + (size_t)b * 32 * NN;
  for (int v = 0; v < nvb; v++)
    cs[v * VSTR + cmap(tid)] = Ck[(size_t)(kin + v0 + v) * NN + tid];
  __syncthreads();
  const int n = rg * 64 + (tid >> 2);
  const int q = tid & 3;
  const float* Pr = P + (size_t)b * NN * NN + (size_t)n * NN + q * 64;
  float m[4] = {INF, INF, INF, INF};
  if (q * 64 + 63 > n) {
    #pragma unroll 4
    for (int i = 0; i < 16; i++) {
      const float4 a = *(const float4*)(Pr + i * 4);
      #pragma unroll
      for (int v = 0; v < 4; v++) {
        if (v < nvb) {
          const float4 c = *(const float4*)&cs[v * VSTR + q * 68 + i * 4];
          m[v] = fminf(m[v], fminf(fminf(a.x + c.x, a.y + c.y),
                                   fminf(a.z + c.z, a.w + c.w)));
        }
      }
    }
  }
  #pragma unroll
  for (int v = 0; v < 4; v++) {
    m[v] = fminf(m[v], __shfl_xor(m[v], 1));
    m[v] = fminf(m[v], __shfl_xor(m[v], 2));
  }
  if (q == 0) {
    for (int v = 0; v < nvb; v++)
      Ck[(size_t)(kout + v0 + v) * NN + n] = fminf(m[v], INF);
  }
}

__global__ __launch_bounds__(256) void tail(
    const float* P1, const float* Q1, float* O1, int nMM,
    const float* SP, float* Cstk, int kin, int kout, int nv)
{
  __shared__ float As[16][64];
  __shared__ float Bs[16][64];
  __shared__ __align__(16) float cs[4 * VSTR];
  const int b = blockIdx.y, zz = blockIdx.z;
  if (zz < nMM)
    mm_tile(P1, Q1, O1, b, blockIdx.x, As, Bs);
  else
    stage_blk(SP, Cstk, b, blockIdx.x, kin, kout, nv, cs);
}

// ---------------- fused softmax: one block per (k, b), rows then cols ----------
__global__ __launch_bounds__(256) void sm_all(
    const float* __restrict__ A, const float* __restrict__ Cstk,
    float* __restrict__ out)
{
  const int k = blockIdx.x + 1;        // 1..29
  const int b = blockIdx.y;
  const int limit = NN - k;
  const int tid = threadIdx.x;
  __shared__ __align__(16) float cprev[VSTR];
  __shared__ float mrow[NN];
  __shared__ float ivh[NN];
  const float* Ckb = Cstk + (size_t)b * 32 * NN;
  cprev[cmap(tid)] = Ckb[(size_t)(k - 1) * NN + tid];
  mrow[tid]        = Ckb[(size_t)k * NN + tid];
  __syncthreads();
  const float* Ab = A + (size_t)b * NN * NN;
  const int r = tid >> 2, q = tid & 3;
  for (int rr = 0; rr < 4; rr++) {
    const int n = rr * 64 + r;
    const float m = mrow[n];
    float s = 0.f;
    if (q * 64 + 63 > n) {
      const float* Ar = Ab + (size_t)n * NN + q * 64;
      #pragma unroll 4
      for (int i = 0; i < 16; i++) {
        const float4 a = *(const float4*)(Ar + i * 4);
        const int jj = q * 64 + i * 4;
        const float4 c = *(const float4*)&cprev[q * 68 + i * 4];
        s += (jj + 0 <= limit) ? __expf(m - a.x - c.x) : 0.f;
        s += (jj + 1 <= limit) ? __expf(m - a.y - c.y) : 0.f;
        s += (jj + 2 <= limit) ? __expf(m - a.z - c.z) : 0.f;
        s += (jj + 3 <= limit) ? __expf(m - a.w - c.w) : 0.f;
      }
    }
    s += __shfl_xor(s, 1);
    s += __shfl_xor(s, 2);
    if (q == 0) ivh[n] = 1.0f / s;
  }
  __syncthreads();
  const int j = tid;
  if (j < limit) {
    const float cj = cprev[cmap(j + 1)];
    const int nmax = (j < limit - 1) ? j : limit - 1;
    float a = 0.0f;
    for (int nr = 0; nr <= nmax; nr++)
      a += __expf(mrow[nr] - Ab[(size_t)nr * NN + j + 1] - cj) * ivh[nr];
    int kmaxj = NN - 1 - j; if (kmaxj > KMAX - 1) kmaxj = KMAX - 1;
    atomicAdd(&out[b * NN + j], a / (float)((j + 1) * kmaxj));
  }
}

extern "C" void kernel_launch(void* const* d_in, const int* in_sizes, int n_in,
                              void* d_out, int out_size, void* d_ws, size_t ws_size,
                              hipStream_t stream) {
  const float* x  = (const float*)d_in[0];
  const float* W0 = (const float*)d_in[1];
  const float* b0 = (const float*)d_in[2];
  const float* W1 = (const float*)d_in[3];
  const float* b1 = (const float*)d_in[4];
  float* out = (float*)d_out;

  // ws layout — non-overlapping, ~24 MB of the 256 MiB workspace
  char* base = (char*)d_ws;
  float*  h    = (float*)(base);                          // 2 MB
  float*  z    = (float*)(base + (2u  << 20));            // 1 MB
  float*  D    = (float*)(base + (3u  << 20));            // 2 MB
  double* R    = (double*)(base + (5u  << 20));           // 4 MB
  double* S    = (double*)(base + (9u  << 20));           // 4 MB
  double* Pg   = (double*)(base + (13u << 20));           // 64 KB
  double* dg   = (double*)(base + (13u << 20) + (128u << 10));  // 16 KB
  float*  A    = (float*)(base + (14u << 20));            // 2 MB
  float*  A2   = (float*)(base + (16u << 20));
  float*  A4   = (float*)(base + (18u << 20));
  float*  A8   = (float*)(base + (20u << 20));
  float*  A16  = (float*)(base + (22u << 20));
  float*  Cstk = (float*)(base + (24u << 20));            // 256 KB

  gemm64<<<dim3(F1/64, ROWS/64), 256, 0, stream>>>(x, W0, b0, h, ROWS, F1, F0, 1);
  gemm64<<<dim3(F2/64, ROWS/64), 256, 0, stream>>>(h, W1, b1, z, ROWS, F2, F1, 0);
  corr_dist<<<dim3(NN/64, NN/64, NB), 256, 0, stream>>>(z, D);
  rowscan_pg<<<dim3(NB*4), 256, 0, stream>>>(D, R, Pg);
  colscan2<<<dim3(4, NB), 256, 0, stream>>>(R, Pg, S, dg);
  dsmat<<<dim3(4, NB), 256, 0, stream>>>(S, dg, A, Cstk, out);
  // T1: A2 = A(x)A; C1 = A(x)C0
  tail<<<dim3(16, NB, 2), 256, 0, stream>>>(A,  A,  A2,  1, A,   Cstk, 0, 1, 1);
  // T2: A4 = A2(x)A2; C2-3 = A2(x)C0-1
  tail<<<dim3(16, NB, 2), 256, 0, stream>>>(A2, A2, A4,  1, A2,  Cstk, 0, 2, 2);
  // T3: A8 = A4(x)A4; C4-7 = A4(x)C0-3
  tail<<<dim3(16, NB, 2), 256, 0, stream>>>(A4, A4, A8,  1, A4,  Cstk, 0, 4, 4);
  // T4: A16 = A8(x)A8; C8-15 = A8(x)C0-7
  tail<<<dim3(16, NB, 2), 256, 0, stream>>>(A8, A8, A16, 1, A8,  Cstk, 0, 8, 8);
  // T5: C16-29 = A16(x)C0-13
  tail<<<dim3(16, NB, 1), 256, 0, stream>>>(nullptr, nullptr, nullptr, 0, A16, Cstk, 0, 16, 14);
  sm_all<<<dim3(KMAX-1, NB), 256, 0, stream>>>(A, Cstk, out);
}